// Round 10
// baseline (540.958 us; speedup 1.0000x reference)
//
#include <hip/hip_runtime.h>
#include <hip/hip_bf16.h>
#include <math.h>

#define N_NODES 100000
#define N_EDGES 1200000
#define NT_POST 6250           // node tiles of 16
#define AVG_D   2.5649493574615367f
#define EPSV    1e-5f

#define BUK_SHIFT 9
#define NBUK 196               // ceil(N_NODES/512)
#define EB_PER_BLOCK 4096      // k_bin edges per block (16/thread)

typedef __attribute__((ext_vector_type(8))) short short8;
typedef __attribute__((ext_vector_type(4))) float f32x4;

struct ERec { unsigned eid, sn, dn; };   // 12 B staging record (k_bin -> k_place)

// ---- workspace layout (bytes), total 101,333,120 (< 135,205,120 proven) ----
#define OFF_DEG       0u              // N u32
#define OFF_ROWLOCAL  400000u
#define OFF_BSUM      800000u         // 2048
#define OFF_BOFFS     802048u
#define OFF_ROWSTART  804096u
#define OFF_CURSOR    1204096u        // 196 u32 bucket cursors (pad to 1024)
#define OFF_EREC      1205120u        // E * 8 B = 9.6 MB  {eid, sn}
#define OFF_AB        10805120u       // N*2 f32
#define OFF_BNACC     11605120u       // 128 f32
#define OFF_BNFIN     11605632u       // 128 f32
#define OFF_HB        11606144u       // N*64 bf16 = 12.8 MB
#define OFF_AGG       24406144u       // N*256 bf16 = 51.2 MB
#define OFF_WFRAG     75606144u       // 20,480 B   (k_node B-frags)
#define OFF_WFRAG2    75626624u       // 106,496 B  (k_post B-frags)
#define OFF_STAGING   75733120u       // E*12 = 14.4 MB (dead after k_place)
#define OFF_OUTPRE    OFF_STAGING     // N*64 f32 = 25.6 MB, aliases staging

__device__ __forceinline__ short f2b(float f){          // fp32 -> bf16 bits (RNE)
    union { float f; unsigned u; } c; c.f = f;
    unsigned u = c.u;
    unsigned r = (u + 0x7fffu + ((u >> 16) & 1u)) >> 16;
    return (short)r;
}
__device__ __forceinline__ unsigned pk(float a, float b){
    return ((unsigned)(unsigned short)f2b(a)) | (((unsigned)(unsigned short)f2b(b)) << 16);
}

// ========== CSR build + h->bf16 + weight-fragment precompute ==========
__global__ void k_prep(const int* __restrict__ dst, unsigned* __restrict__ deg,
                       const float* __restrict__ h, unsigned short* __restrict__ hb,
                       const float* __restrict__ W_pre, unsigned short* __restrict__ wfrag,
                       const float* __restrict__ W_post, unsigned short* __restrict__ wfrag2){
    int i = blockIdx.x*256 + threadIdx.x;
    if (i < N_EDGES) atomicAdd(&deg[dst[i]], 1u);
    if (i < 800000){                                    // 8 floats per thread
        const float4* p = (const float4*)h + (size_t)i*2;
        float4 u0 = p[0], u1 = p[1];
        uint4 o;
        o.x = pk(u0.x,u0.y); o.y = pk(u0.z,u0.w);
        o.z = pk(u1.x,u1.y); o.w = pk(u1.z,u1.w);
        ((uint4*)hb)[i] = o;
    }
    // W_pre fragments: layout ((ks*4+cg)*64 + lane)*8 + e ; K padded 144->160
    if (i < 10240){
        int e = i & 7, l = (i>>3) & 63, q = i>>9;       // q = ks*4+cg
        int ks = q>>2, cg = q&3;
        int lr = l&15, lg = l>>4;
        int k = ks*32 + lg*8 + e, col = cg*16 + lr;
        wfrag[i] = (unsigned short)((k < 144) ? f2b(W_pre[k*64 + col]) : (short)0);
    }
    // W_post fragments: layout ((f*4+cg)*64 + lane)*8 + e ; f<10:Bm, 10..17:B2, 18..25:B3
    if (i < 53248){
        int e = i & 7, l = (i>>3) & 63, g = i>>9;       // g = f*4+cg
        int cg = g & 3, f = g>>2;
        int lr = l&15, lg = l>>4;
        int col = cg*16 + lr;
        int row;
        if      (f < 10) row = f*32        + lg*8 + e;
        else if (f < 18) row = 320 + (f-10)*32 + lg*8 + e;
        else             row = 576 + (f-18)*32 + lg*8 + e;
        wfrag2[i] = (unsigned short)f2b(W_post[row*64 + col]);
    }
}
__global__ void k_scan1(const unsigned* __restrict__ deg, unsigned* __restrict__ rowlocal,
                        unsigned* __restrict__ bsum){
    __shared__ unsigned s[256];
    int t = threadIdx.x; int i = blockIdx.x*256 + t;
    unsigned d = (i < N_NODES) ? deg[i] : 0u;
    s[t] = d; __syncthreads();
    for (int off=1; off<256; off<<=1){
        unsigned v = (t>=off) ? s[t-off] : 0u; __syncthreads();
        s[t] += v; __syncthreads();
    }
    if (i < N_NODES) rowlocal[i] = s[t] - d;
    if (t == 255) bsum[blockIdx.x] = s[255];
}
__global__ void k_scan2(const unsigned* __restrict__ bsum, unsigned* __restrict__ boffs){
    __shared__ unsigned s[512];
    int t = threadIdx.x;
    unsigned v = (t < 391) ? bsum[t] : 0u;
    s[t] = v; __syncthreads();
    for (int off=1; off<512; off<<=1){
        unsigned x = (t>=off) ? s[t-off] : 0u; __syncthreads();
        s[t] += x; __syncthreads();
    }
    boffs[t] = s[t] - v;
}
__global__ void k_scan3(const unsigned* __restrict__ rowlocal, const unsigned* __restrict__ boffs,
                        unsigned* __restrict__ rowstart, unsigned* __restrict__ bukCursor){
    int i = blockIdx.x*256 + threadIdx.x;
    if (i < N_NODES){
        unsigned v = rowlocal[i] + boffs[i>>8];
        rowstart[i] = v;
        if ((i & 511) == 0) bukCursor[i>>BUK_SHIFT] = v;   // bucket staging base
    }
}

// ========== phase B: bin edges by dst-bucket into staging (chunk-reserved, L2-merging) ====
__global__ __launch_bounds__(256) void k_bin(
    const int* __restrict__ src, const int* __restrict__ dst,
    unsigned* __restrict__ bukCursor, ERec* __restrict__ staging)
{
    __shared__ unsigned hist[NBUK];
    __shared__ unsigned gbase[NBUK];
    int tid = threadIdx.x;
    for (int j=tid; j<NBUK; j+=256) hist[j]=0u;
    __syncthreads();
    int base = blockIdx.x*EB_PER_BLOCK;                // grid 293 -> covers E
    int sn[16], dn[16];
    #pragma unroll
    for (int k=0;k<16;k++){
        int i = base + k*256 + tid;                    // coalesced
        if (i < N_EDGES){
            sn[k]=src[i]; dn[k]=dst[i];
            atomicAdd(&hist[dn[k]>>BUK_SHIFT],1u);
        } else dn[k] = -1;
    }
    __syncthreads();
    for (int j=tid; j<NBUK; j+=256){
        unsigned c = hist[j];
        gbase[j] = c ? atomicAdd(&bukCursor[j], c) : 0u;
        hist[j] = 0u;                                  // reuse as local cursor
    }
    __syncthreads();
    #pragma unroll
    for (int k=0;k<16;k++){
        int i = base + k*256 + tid;
        if (i < N_EDGES){
            int b = dn[k]>>BUK_SHIFT;
            unsigned off = atomicAdd(&hist[b],1u);
            ERec r; r.eid=(unsigned)i; r.sn=(unsigned)sn[k]; r.dn=(unsigned)dn[k];
            staging[gbase[b]+off] = r;
        }
    }
}

// ========== phase C: per-bucket placement into CSR order; strip dn -> 8B record ==========
__global__ __launch_bounds__(256) void k_place(
    const ERec* __restrict__ staging, const unsigned* __restrict__ rowstart,
    uint2* __restrict__ erec)
{
    __shared__ unsigned cur[512];
    int b = blockIdx.x;                                // grid == NBUK, bucket-exclusive
    int nbase = b<<BUK_SHIFT;
    int nend  = nbase + 512; if (nend > N_NODES) nend = N_NODES;
    int tid = threadIdx.x;
    for (int j=tid; j<512; j+=256)
        cur[j] = (nbase+j < N_NODES) ? rowstart[nbase+j] : (unsigned)N_EDGES;
    __syncthreads();
    unsigned p0 = rowstart[nbase];
    unsigned p1 = (nend < N_NODES) ? rowstart[nend] : (unsigned)N_EDGES;
    for (unsigned p = p0 + tid; p < p1; p += 256){
        ERec r = staging[p];
        unsigned pos = atomicAdd(&cur[r.dn - nbase], 1u);
        erec[pos] = make_uint2(r.eid, r.sn);
    }
}

// ========== FUSED edge GEMM + aggregation: one wave per node, no m materialization =======
__global__ __launch_bounds__(256) void k_node(
    const unsigned short* __restrict__ hb, const float* __restrict__ e_in,
    const unsigned short* __restrict__ wfrag, const float* __restrict__ b_pre,
    const uint2* __restrict__ erec, const unsigned* __restrict__ rowstart,
    const unsigned* __restrict__ deg, unsigned short* __restrict__ agg,
    float* __restrict__ ab)
{
    __shared__ __align__(16) uint4 wfl[1280];            // 20,480 B: W_pre frags
    int tid = threadIdx.x;
    int wv = tid>>6, l = tid&63, lr = l&15, lg = l>>4;
    for (int j=tid; j<1280; j+=256) wfl[j] = ((const uint4*)wfrag)[j];
    __syncthreads();
    const short8* B = (const short8*)wfl;
    float bias[4];
    #pragma unroll
    for (int cg=0; cg<4; cg++) bias[cg] = b_pre[cg*16 + lr];

    for (int node = blockIdx.x*4 + wv; node < N_NODES; node += gridDim.x*4){
        unsigned start = rowstart[node];
        int d = (int)deg[node];                          // d >= 1; max ~45 (1+Poisson(11))
        const unsigned short* pn = hb + (size_t)node*64 + lg*8;
        short8 D0 = *(const short8*)pn;                  // h[dst]=h[node]: wave-broadcast
        short8 D1 = *(const short8*)(pn + 32);
        float s1[4], s2[4], mx[4], mn[4];
        #pragma unroll
        for (int cg=0; cg<4; cg++){
            s1[cg]=0.f; s2[cg]=0.f; mx[cg]=-3.402823466e38f; mn[cg]=3.402823466e38f;
        }
        for (int base=0; base<d; base+=16){              // <=3 tiles typically 1
            int rem = d - base;
            short8 A0={0,0,0,0,0,0,0,0}, A1={0,0,0,0,0,0,0,0}, A4={0,0,0,0,0,0,0,0};
            if (lr < rem){                               // pad rows: zero frags, no loads
                uint2 er = erec[start + base + lr];      // {eid, sn}; A row = lr
                const unsigned short* ps = hb + (size_t)er.y*64 + lg*8;
                A0 = *(const short8*)ps;
                A1 = *(const short8*)(ps + 32);
                if (lg < 2){
                    const float* pe = e_in + (size_t)er.x*16 + lg*8;
                    float4 u0 = *(const float4*)pe, u1 = *(const float4*)(pe+4);
                    A4[0]=f2b(u0.x); A4[1]=f2b(u0.y); A4[2]=f2b(u0.z); A4[3]=f2b(u0.w);
                    A4[4]=f2b(u1.x); A4[5]=f2b(u1.y); A4[6]=f2b(u1.z); A4[7]=f2b(u1.w);
                }
            }
            f32x4 acc[4];
            #pragma unroll
            for (int cg=0; cg<4; cg++) acc[cg] = (f32x4){0.f,0.f,0.f,0.f};
            #pragma unroll
            for (int cg=0; cg<4; cg++) acc[cg] = __builtin_amdgcn_mfma_f32_16x16x32_bf16(A0, B[(0*4+cg)*64+l], acc[cg], 0,0,0);
            #pragma unroll
            for (int cg=0; cg<4; cg++) acc[cg] = __builtin_amdgcn_mfma_f32_16x16x32_bf16(A1, B[(1*4+cg)*64+l], acc[cg], 0,0,0);
            #pragma unroll
            for (int cg=0; cg<4; cg++) acc[cg] = __builtin_amdgcn_mfma_f32_16x16x32_bf16(D0, B[(2*4+cg)*64+l], acc[cg], 0,0,0);
            #pragma unroll
            for (int cg=0; cg<4; cg++) acc[cg] = __builtin_amdgcn_mfma_f32_16x16x32_bf16(D1, B[(3*4+cg)*64+l], acc[cg], 0,0,0);
            #pragma unroll
            for (int cg=0; cg<4; cg++) acc[cg] = __builtin_amdgcn_mfma_f32_16x16x32_bf16(A4, B[(4*4+cg)*64+l], acc[cg], 0,0,0);
            // stats over valid rows (row = base + 4*lg + rr < d); f32 accumulation
            #pragma unroll
            for (int rr=0; rr<4; rr++){
                bool v = (base + lg*4 + rr) < d;
                #pragma unroll
                for (int cg=0; cg<4; cg++){
                    float m = acc[cg][rr] + bias[cg];
                    if (v){
                        s1[cg] += m; s2[cg] = fmaf(m,m,s2[cg]);
                        mx[cg] = fmaxf(mx[cg],m); mn[cg] = fminf(mn[cg],m);
                    }
                }
            }
        }
        // fold rows across lg groups: lanes {l, l^16, l^32, l^48} share col lr
        #pragma unroll
        for (int cg=0; cg<4; cg++){
            s1[cg] += __shfl_xor(s1[cg],16); s1[cg] += __shfl_xor(s1[cg],32);
            s2[cg] += __shfl_xor(s2[cg],16); s2[cg] += __shfl_xor(s2[cg],32);
            mx[cg] = fmaxf(mx[cg],__shfl_xor(mx[cg],16)); mx[cg] = fmaxf(mx[cg],__shfl_xor(mx[cg],32));
            mn[cg] = fminf(mn[cg],__shfl_xor(mn[cg],16)); mn[cg] = fminf(mn[cg],__shfl_xor(mn[cg],32));
        }
        if (l < 16){
            float Dv = (float)d;
            unsigned short* ag = agg + (size_t)node*256;
            #pragma unroll
            for (int cg=0; cg<4; cg++){
                float mean = s1[cg]/Dv;
                float sd = sqrtf(fmaxf(s2[cg]/Dv - mean*mean, 0.f) + EPSV);
                ag[      cg*16 + lr] = (unsigned short)f2b(mean);
                ag[ 64 + cg*16 + lr] = (unsigned short)f2b(mx[cg]);
                ag[128 + cg*16 + lr] = (unsigned short)f2b(mn[cg]);
                ag[192 + cg*16 + lr] = (unsigned short)f2b(sd);
            }
            if (l == 0){
                float logd = logf(Dv + 1.f);
                ab[node*2]   = logd / AVG_D;
                ab[node*2+1] = AVG_D / logd;
            }
        }
    }
}

// ========== post GEMM: one column-group per block, B-frags in LDS ==========
__global__ __launch_bounds__(256) void k_post(
    const unsigned short* __restrict__ hb, const unsigned short* __restrict__ agg,
    const unsigned short* __restrict__ wfrag2,
    const float* __restrict__ ab, const float* __restrict__ snorm,
    const float* __restrict__ b_post,
    float* __restrict__ out_pre, float* __restrict__ bn_acc)
{
    __shared__ __align__(16) uint4 wfs[1664];            // 26 frags x 64 lanes = 26.6 KB
    int tid = threadIdx.x;
    int cg = blockIdx.x & 3;                             // block owns one column group
    int bg = blockIdx.x >> 2;                            // 0..390
    int wv = tid>>6, l = tid&63, lr = l&15, lg = l>>4;
    for (int j=tid; j<1664; j+=256){
        int f = j>>6, ll = j&63;
        wfs[j] = ((const uint4*)wfrag2)[(size_t)(f*4 + cg)*64 + ll];
    }
    __syncthreads();
    const short8* B = (const short8*)wfs;
    int col = cg*16 + lr;
    float bias = b_post[col];
    float bs = 0.f, bq = 0.f;

    for (int t = bg*4 + wv; t < NT_POST; t += 1564){     // grid 1564 = 391*4
        int nodeA = t*16 + lr;                           // A row = lane&15
        f32x4 aM = {0.f,0.f,0.f,0.f}, a2 = {0.f,0.f,0.f,0.f}, a3 = {0.f,0.f,0.f,0.f};
        #pragma unroll
        for (int ks=0; ks<2; ks++){                      // h part
            short8 A = *(const short8*)(hb + (size_t)nodeA*64 + ks*32 + lg*8);
            aM = __builtin_amdgcn_mfma_f32_16x16x32_bf16(A, B[ks*64 + l], aM, 0,0,0);
        }
        #pragma unroll
        for (int ks=0; ks<8; ks++){                      // agg part
            short8 A = *(const short8*)(agg + (size_t)nodeA*256 + ks*32 + lg*8);
            aM = __builtin_amdgcn_mfma_f32_16x16x32_bf16(A, B[( 2+ks)*64 + l], aM, 0,0,0);
            a2 = __builtin_amdgcn_mfma_f32_16x16x32_bf16(A, B[(10+ks)*64 + l], a2, 0,0,0);
            a3 = __builtin_amdgcn_mfma_f32_16x16x32_bf16(A, B[(18+ks)*64 + l], a3, 0,0,0);
        }
        #pragma unroll
        for (int r=0; r<4; r++){
            int node = t*16 + lg*4 + r;                  // D row = 4*lg + r
            float av = ab[node*2], bv = ab[node*2+1];
            float v = (aM[r] + av*a2[r] + bv*a3[r] + bias) * snorm[node];
            out_pre[(size_t)node*64 + col] = v;
            bs += v; bq = fmaf(v,v,bq);
        }
    }
    bs += __shfl_xor(bs, 16); bs += __shfl_xor(bs, 32);
    bq += __shfl_xor(bq, 16); bq += __shfl_xor(bq, 32);
    if (l < 16){
        atomicAdd(&bn_acc[col], bs);
        atomicAdd(&bn_acc[64 + col], bq);
    }
}

// ========== BatchNorm finalize + apply ==========
__global__ void k_bnfin(const float* __restrict__ bn_acc, const float* __restrict__ gamma,
                        const float* __restrict__ beta, float* __restrict__ bn_fin){
    int c = threadIdx.x;
    float invN = 1.f/(float)N_NODES;
    float mu = bn_acc[c]*invN;
    float ms = bn_acc[64+c]*invN;
    float var = fmaxf(ms - mu*mu, 0.f);
    float scale = gamma[c] / sqrtf(var + 1e-5f);
    bn_fin[c] = scale;
    bn_fin[64+c] = beta[c] - mu*scale;
}
__global__ void k_apply(const float* __restrict__ out_pre, const float* __restrict__ bn_fin,
                        float* __restrict__ out){
    int i = blockIdx.x*256 + threadIdx.x;     // float4 index; 6250*256*4 == N*64
    int c4 = (i & 15) * 4;
    float4 v  = ((const float4*)out_pre)[i];
    float4 sc = *(const float4*)&bn_fin[c4];
    float4 sh = *(const float4*)&bn_fin[64 + c4];
    float4 o;
    o.x = fmaf(v.x, sc.x, sh.x); o.y = fmaf(v.y, sc.y, sh.y);
    o.z = fmaf(v.z, sc.z, sh.z); o.w = fmaf(v.w, sc.w, sh.w);
    ((float4*)out)[i] = o;
}

extern "C" void kernel_launch(void* const* d_in, const int* in_sizes, int n_in,
                              void* d_out, int out_size, void* d_ws, size_t ws_size,
                              hipStream_t stream)
{
    const float* h      = (const float*)d_in[0];
    const float* e_in   = (const float*)d_in[1];
    const float* snorm  = (const float*)d_in[2];
    const float* W_pre  = (const float*)d_in[3];
    const float* b_pre  = (const float*)d_in[4];
    const float* W_post = (const float*)d_in[5];
    const float* b_post = (const float*)d_in[6];
    const float* gamma  = (const float*)d_in[7];
    const float* beta   = (const float*)d_in[8];
    const int*   src    = (const int*)d_in[9];
    const int*   dst    = (const int*)d_in[10];

    char* ws = (char*)d_ws;
    unsigned* deg      = (unsigned*)(ws + OFF_DEG);
    unsigned* rowlocal = (unsigned*)(ws + OFF_ROWLOCAL);
    unsigned* bsum     = (unsigned*)(ws + OFF_BSUM);
    unsigned* boffs    = (unsigned*)(ws + OFF_BOFFS);
    unsigned* rowstart = (unsigned*)(ws + OFF_ROWSTART);
    unsigned* bukCur   = (unsigned*)(ws + OFF_CURSOR);
    uint2*    erec     = (uint2*)(ws + OFF_EREC);
    ERec*     staging  = (ERec*)(ws + OFF_STAGING);
    float*    abuf     = (float*)(ws + OFF_AB);
    float*    bnacc    = (float*)(ws + OFF_BNACC);
    float*    bnfin    = (float*)(ws + OFF_BNFIN);
    unsigned short* hb     = (unsigned short*)(ws + OFF_HB);
    unsigned short* aggp   = (unsigned short*)(ws + OFF_AGG);
    unsigned short* wfrag  = (unsigned short*)(ws + OFF_WFRAG);
    unsigned short* wfrag2 = (unsigned short*)(ws + OFF_WFRAG2);
    float*    outpre   = (float*)(ws + OFF_OUTPRE);

    hipMemsetAsync(ws + OFF_DEG,   0, 400000, stream);
    hipMemsetAsync(ws + OFF_BNACC, 0, 512,    stream);

    k_prep   <<<4688, 256, 0, stream>>>(dst, deg, h, hb, W_pre, wfrag, W_post, wfrag2);
    k_scan1  <<<391,  256, 0, stream>>>(deg, rowlocal, bsum);
    k_scan2  <<<1,    512, 0, stream>>>(bsum, boffs);
    k_scan3  <<<391,  256, 0, stream>>>(rowlocal, boffs, rowstart, bukCur);
    k_bin    <<<293,  256, 0, stream>>>(src, dst, bukCur, staging);
    k_place  <<<NBUK, 256, 0, stream>>>(staging, rowstart, erec);

    k_node   <<<3125, 256, 0, stream>>>(hb, e_in, wfrag, b_pre, erec, rowstart, deg, aggp, abuf);

    k_post   <<<1564, 256, 0, stream>>>(hb, aggp, wfrag2, abuf, snorm, b_post, outpre, bnacc);
    k_bnfin  <<<1,    64,  0, stream>>>(bnacc, gamma, beta, bnfin);
    k_apply  <<<6250, 256, 0, stream>>>(outpre, bnfin, (float*)d_out);
}